// Round 1
// baseline (1407.878 us; speedup 1.0000x reference)
//
#include <hip/hip_runtime.h>

#define N_NODES 100000
#define N_EDGES 3200000
#define IN_F    128
#define EDGE_F  16
#define OUT_F   128
#define K_TOT   144   // IN_F + EDGE_F

// ---- workspace layout (bytes) ----
// counts  : int[100000]            @ 0
// offsets : int[100001]            @ 400000
// partials: int[256]               @ 800016
// cursors : int[100000]            @ 801040
// csr     : int[3200000]           @ 1201040
// Se      : float[100000*16]       @ 14001040
// total ~ 20.4 MB

__global__ void count_k(const int* __restrict__ col, int* __restrict__ counts) {
    int e = blockIdx.x * blockDim.x + threadIdx.x;
    if (e < N_EDGES) atomicAdd(&counts[col[e]], 1);
}

// per-chunk (512) exclusive scan; chunk totals -> partials
__global__ void scan1_k(const int* __restrict__ counts, int* __restrict__ offsets,
                        int* __restrict__ partials) {
    __shared__ int s[512];
    int i = blockIdx.x * 512 + threadIdx.x;
    int v = (i < N_NODES) ? counts[i] : 0;
    s[threadIdx.x] = v;
    __syncthreads();
    for (int d = 1; d < 512; d <<= 1) {
        int t = (threadIdx.x >= d) ? s[threadIdx.x - d] : 0;
        __syncthreads();
        s[threadIdx.x] += t;
        __syncthreads();
    }
    if (i < N_NODES) offsets[i] = s[threadIdx.x] - v;   // exclusive within chunk
    if (threadIdx.x == 511) partials[blockIdx.x] = s[511];
}

// exclusive scan of the 196 chunk totals (single block)
__global__ void scan2_k(int* partials) {
    __shared__ int s[256];
    int v = (threadIdx.x < 196) ? partials[threadIdx.x] : 0;
    s[threadIdx.x] = v;
    __syncthreads();
    for (int d = 1; d < 256; d <<= 1) {
        int t = (threadIdx.x >= d) ? s[threadIdx.x - d] : 0;
        __syncthreads();
        s[threadIdx.x] += t;
        __syncthreads();
    }
    if (threadIdx.x < 196) partials[threadIdx.x] = s[threadIdx.x] - v;
}

__global__ void scan3_k(int* __restrict__ offsets, const int* __restrict__ partials,
                        int* __restrict__ cursors) {
    int i = blockIdx.x * 512 + threadIdx.x;
    if (i < N_NODES) {
        int o = offsets[i] + partials[blockIdx.x];
        offsets[i] = o;
        cursors[i] = o;
    }
    if (i == 0) offsets[N_NODES] = N_EDGES;
}

__global__ void fill_k(const int* __restrict__ col, int* __restrict__ cursors,
                       int* __restrict__ csr) {
    int e = blockIdx.x * blockDim.x + threadIdx.x;
    if (e < N_EDGES) {
        int pos = atomicAdd(&cursors[col[e]], 1);
        csr[pos] = e;
    }
}

// one wave (64 lanes) per node: accumulate S_x (2 floats/lane) and S_e in regs.
__global__ void gather_k(const float* __restrict__ x, const int* __restrict__ row,
                         const float* __restrict__ ea, const int* __restrict__ offsets,
                         const int* __restrict__ csr,
                         float* __restrict__ Sx, float* __restrict__ Se) {
    int wave = threadIdx.x >> 6;
    int lane = threadIdx.x & 63;
    int n = blockIdx.x * 4 + wave;   // 25000 blocks * 4 waves = 100000 exactly

    int off0 = offsets[n];
    int off1 = offsets[n + 1];

    float2 acc = make_float2(0.f, 0.f);
    float4 se  = make_float4(0.f, 0.f, 0.f, 0.f);

    float2 vcur = make_float2(0.f, 0.f);
    float4 wcur = make_float4(0.f, 0.f, 0.f, 0.f);
    if (off0 < off1) {
        int e = csr[off0];
        int r = row[e];
        vcur = ((const float2*)(x + (size_t)r * IN_F))[lane];
        if (lane < 4) wcur = ((const float4*)(ea + (size_t)e * EDGE_F))[lane];
    }
    for (int p = off0; p < off1; ++p) {
        float2 vn = make_float2(0.f, 0.f);
        float4 wn = make_float4(0.f, 0.f, 0.f, 0.f);
        if (p + 1 < off1) {           // prefetch next edge one iteration ahead
            int e = csr[p + 1];
            int r = row[e];
            vn = ((const float2*)(x + (size_t)r * IN_F))[lane];
            if (lane < 4) wn = ((const float4*)(ea + (size_t)e * EDGE_F))[lane];
        }
        acc.x += vcur.x; acc.y += vcur.y;
        se.x += wcur.x; se.y += wcur.y; se.z += wcur.z; se.w += wcur.w;
        vcur = vn; wcur = wn;
    }

    ((float2*)(Sx + (size_t)n * IN_F))[lane] = acc;
    if (lane < 4) ((float4*)(Se + (size_t)n * EDGE_F))[lane] = se;
}

// [100000 x 144] @ [144 x 128]^T-ish GEMM with per-node deg*b bias and /deg.
// Block: 256 thr = (to 0..31: 4 outputs) x (tn 0..7: 4 nodes). Tile = 32 nodes.
// In-place on d_out: each block stages its own S rows to LDS before overwriting.
#define TILE_N 32
__global__ __launch_bounds__(256) void gemm_k(
        const float* __restrict__ Sx, const float* __restrict__ Se,
        const int* __restrict__ offsets, const float* __restrict__ W,
        const float* __restrict__ b, float* __restrict__ out) {
    __shared__ float Wt[72 * 132];   // half of W, transposed [k][o], padded row 132
    __shared__ float Sl[144 * 36];   // S tile transposed [k][n], padded row 36

    int tid = threadIdx.x;
    int to4 = (tid & 31) * 4;
    int tn  = tid >> 5;
    int tn4 = tn * 4;
    int ntiles = N_NODES / TILE_N;   // 3125

    for (int tile = blockIdx.x; tile < ntiles; tile += gridDim.x) {
        int n0 = tile * TILE_N;
        __syncthreads();             // prev tile's readers done before Sl overwrite

        // stage Sx rows (coalesced read, transposed LDS write)
        for (int idx = tid; idx < TILE_N * IN_F; idx += 256) {
            int n = idx >> 7, k = idx & 127;
            Sl[k * 36 + n] = Sx[(size_t)(n0 + n) * IN_F + k];
        }
        // stage Se rows
        for (int idx = tid; idx < TILE_N * EDGE_F; idx += 256) {
            int n = idx >> 4, k = idx & 15;
            Sl[(IN_F + k) * 36 + n] = Se[(size_t)(n0 + n) * EDGE_F + k];
        }

        float4 a0 = make_float4(0,0,0,0), a1 = make_float4(0,0,0,0);
        float4 a2 = make_float4(0,0,0,0), a3 = make_float4(0,0,0,0);

        for (int half = 0; half < 2; ++half) {
            __syncthreads();   // S staged (half 0) / prev half compute done
            int kbase = half * 72;
            for (int idx = tid; idx < 72 * 128; idx += 256) {
                int o = idx / 72, kl = idx % 72;          // coalesced W read
                Wt[kl * 132 + o] = W[(size_t)o * K_TOT + kbase + kl];
            }
            __syncthreads();

            #pragma unroll 4
            for (int kl = 0; kl < 72; ++kl) {
                float4 w4 = *(const float4*)&Wt[kl * 132 + to4];
                float4 s4 = *(const float4*)&Sl[(kbase + kl) * 36 + tn4];
                a0.x += s4.x * w4.x; a0.y += s4.x * w4.y; a0.z += s4.x * w4.z; a0.w += s4.x * w4.w;
                a1.x += s4.y * w4.x; a1.y += s4.y * w4.y; a1.z += s4.y * w4.z; a1.w += s4.y * w4.w;
                a2.x += s4.z * w4.x; a2.y += s4.z * w4.y; a2.z += s4.z * w4.z; a2.w += s4.z * w4.w;
                a3.x += s4.w * w4.x; a3.y += s4.w * w4.y; a3.z += s4.w * w4.z; a3.w += s4.w * w4.w;
            }
        }

        float4 b4 = *(const float4*)&b[to4];
        float4 accs[4] = {a0, a1, a2, a3};
        #pragma unroll
        for (int j = 0; j < 4; ++j) {
            int n = n0 + tn4 + j;
            float fdeg = (float)(offsets[n + 1] - offsets[n]);
            float inv = 1.0f / fmaxf(fdeg, 1.0f);
            float4 o4;
            o4.x = (accs[j].x + fdeg * b4.x) * inv;
            o4.y = (accs[j].y + fdeg * b4.y) * inv;
            o4.z = (accs[j].z + fdeg * b4.z) * inv;
            o4.w = (accs[j].w + fdeg * b4.w) * inv;
            *(float4*)&out[(size_t)n * OUT_F + to4] = o4;
        }
    }
}

extern "C" void kernel_launch(void* const* d_in, const int* in_sizes, int n_in,
                              void* d_out, int out_size, void* d_ws, size_t ws_size,
                              hipStream_t stream) {
    const float* x  = (const float*)d_in[0];
    const int*   ei = (const int*)d_in[1];     // int32 per harness convention
    const float* ea = (const float*)d_in[2];
    const float* W  = (const float*)d_in[3];
    const float* b  = (const float*)d_in[4];
    float* out = (float*)d_out;

    char* ws = (char*)d_ws;
    int*   counts   = (int*)(ws + 0);
    int*   offsets  = (int*)(ws + 400000);
    int*   partials = (int*)(ws + 800016);
    int*   cursors  = (int*)(ws + 801040);
    int*   csr      = (int*)(ws + 1201040);
    float* Se       = (float*)(ws + 14001040);

    const int* row = ei;             // edge_index[0]
    const int* col = ei + N_EDGES;   // edge_index[1]

    hipMemsetAsync(counts, 0, N_NODES * sizeof(int), stream);
    count_k<<<(N_EDGES + 255) / 256, 256, 0, stream>>>(col, counts);
    scan1_k<<<196, 512, 0, stream>>>(counts, offsets, partials);
    scan2_k<<<1, 256, 0, stream>>>(partials);
    scan3_k<<<196, 512, 0, stream>>>(offsets, partials, cursors);
    fill_k<<<(N_EDGES + 255) / 256, 256, 0, stream>>>(col, cursors, csr);
    gather_k<<<N_NODES / 4, 256, 0, stream>>>(x, row, ea, offsets, csr, out, Se);
    gemm_k<<<3125, 256, 0, stream>>>(out, Se, offsets, W, b, out);
}

// Round 2
// 1133.448 us; speedup vs baseline: 1.2421x; 1.2421x over previous
//
#include <hip/hip_runtime.h>

#define N_NODES 100000
#define N_EDGES 3200000
#define IN_F    128
#define EDGE_F  16
#define OUT_F   128
#define K_TOT   144   // IN_F + EDGE_F

// ---- workspace layout (bytes) ----
// counts  : int[100000]            @ 0
// offsets : int[100001]            @ 400000
// partials: int[256]               @ 800016
// cursors : int[100000]            @ 801040
// csr     : int[3200000]           @ 1201040
// Se      : float[100000*16]       @ 14001040
// total ~ 20.4 MB

__global__ void count_k(const int* __restrict__ col, int* __restrict__ counts) {
    int e = blockIdx.x * blockDim.x + threadIdx.x;
    if (e < N_EDGES) atomicAdd(&counts[col[e]], 1);
}

// per-chunk (512) exclusive scan; chunk totals -> partials
__global__ void scan1_k(const int* __restrict__ counts, int* __restrict__ offsets,
                        int* __restrict__ partials) {
    __shared__ int s[512];
    int i = blockIdx.x * 512 + threadIdx.x;
    int v = (i < N_NODES) ? counts[i] : 0;
    s[threadIdx.x] = v;
    __syncthreads();
    for (int d = 1; d < 512; d <<= 1) {
        int t = (threadIdx.x >= d) ? s[threadIdx.x - d] : 0;
        __syncthreads();
        s[threadIdx.x] += t;
        __syncthreads();
    }
    if (i < N_NODES) offsets[i] = s[threadIdx.x] - v;   // exclusive within chunk
    if (threadIdx.x == 511) partials[blockIdx.x] = s[511];
}

// exclusive scan of the 196 chunk totals (single block)
__global__ void scan2_k(int* partials) {
    __shared__ int s[256];
    int v = (threadIdx.x < 196) ? partials[threadIdx.x] : 0;
    s[threadIdx.x] = v;
    __syncthreads();
    for (int d = 1; d < 256; d <<= 1) {
        int t = (threadIdx.x >= d) ? s[threadIdx.x - d] : 0;
        __syncthreads();
        s[threadIdx.x] += t;
        __syncthreads();
    }
    if (threadIdx.x < 196) partials[threadIdx.x] = s[threadIdx.x] - v;
}

__global__ void scan3_k(int* __restrict__ offsets, const int* __restrict__ partials,
                        int* __restrict__ cursors) {
    int i = blockIdx.x * 512 + threadIdx.x;
    if (i < N_NODES) {
        int o = offsets[i] + partials[blockIdx.x];
        offsets[i] = o;
        cursors[i] = o;
    }
    if (i == 0) offsets[N_NODES] = N_EDGES;
}

__global__ void fill_k(const int* __restrict__ col, int* __restrict__ cursors,
                       int* __restrict__ csr) {
    int e = blockIdx.x * blockDim.x + threadIdx.x;
    if (e < N_EDGES) {
        int pos = atomicAdd(&cursors[col[e]], 1);
        csr[pos] = e;
    }
}

// one wave per node. Edge ids + row ids bulk-loaded lane-parallel (2 coalesced
// loads per 64 edges), broadcast via shfl (register-only), then 8-deep
// independent x-row loads to hide L2/L3 latency.
__global__ void gather_k(const float* __restrict__ x, const int* __restrict__ row,
                         const float* __restrict__ ea, const int* __restrict__ offsets,
                         const int* __restrict__ csr,
                         float* __restrict__ Sx, float* __restrict__ Se) {
    int wave = threadIdx.x >> 6;
    int lane = threadIdx.x & 63;
    int n = blockIdx.x * 4 + wave;   // 25000 blocks * 4 waves = 100000 exactly

    int off0 = offsets[n];
    int deg  = offsets[n + 1] - off0;

    float accx = 0.f, accy = 0.f;
    float se = 0.f;                  // lanes 0..15 hold Se[n][lane]

    for (int base = 0; base < deg; base += 64) {
        int m = deg - base; if (m > 64) m = 64;
        int e = 0, r = 0;
        if (lane < m) {
            e = csr[off0 + base + lane];   // coalesced: 64 edge ids in 1 load
            r = row[e];                    // 1 dependent gather, amortized /64
        }
        int j = 0;
        for (; j + 8 <= m; j += 8) {
            float2 v0, v1, v2, v3, v4, v5, v6, v7;
            float w0 = 0, w1 = 0, w2 = 0, w3 = 0, w4 = 0, w5 = 0, w6 = 0, w7 = 0;
            #define LOADJ(i, vi, wi)                                            \
                {                                                               \
                    int rj = __shfl(r, j + i);                                  \
                    int ej = __shfl(e, j + i);                                  \
                    vi = ((const float2*)(x + (size_t)rj * IN_F))[lane];        \
                    if (lane < 16) wi = ea[(size_t)ej * EDGE_F + lane];         \
                }
            LOADJ(0, v0, w0) LOADJ(1, v1, w1) LOADJ(2, v2, w2) LOADJ(3, v3, w3)
            LOADJ(4, v4, w4) LOADJ(5, v5, w5) LOADJ(6, v6, w6) LOADJ(7, v7, w7)
            accx += v0.x + v1.x + v2.x + v3.x + v4.x + v5.x + v6.x + v7.x;
            accy += v0.y + v1.y + v2.y + v3.y + v4.y + v5.y + v6.y + v7.y;
            se   += w0 + w1 + w2 + w3 + w4 + w5 + w6 + w7;
        }
        for (; j < m; ++j) {
            int rj = __shfl(r, j);
            int ej = __shfl(e, j);
            float2 v = ((const float2*)(x + (size_t)rj * IN_F))[lane];
            accx += v.x; accy += v.y;
            if (lane < 16) se += ea[(size_t)ej * EDGE_F + lane];
        }
    }

    float2 acc = make_float2(accx, accy);
    ((float2*)(Sx + (size_t)n * IN_F))[lane] = acc;
    if (lane < 16) Se[(size_t)n * EDGE_F + lane] = se;
}

// [100000 x 144] @ [144 x 128]^T GEMM with per-node deg*b bias and /deg.
// Block: 256 thr = (to 0..31: 4 outputs) x (tn 0..7: 4 nodes). Tile = 32 nodes.
// One tile per block (grid 3125). In-place on d_out: block stages its own S
// rows to LDS before overwriting them.
#define TILE_N 32
__global__ __launch_bounds__(256) void gemm_k(
        const float* __restrict__ Sx, const float* __restrict__ Se,
        const int* __restrict__ offsets, const float* __restrict__ W,
        const float* __restrict__ b, float* __restrict__ out) {
    __shared__ float Wt[72 * 132];   // half of W, transposed [k][o], padded row 132
    __shared__ float Sl[144 * 36];   // S tile transposed [k][n], padded row 36

    int tid = threadIdx.x;
    int to4 = (tid & 31) * 4;
    int tn4 = (tid >> 5) * 4;
    int n0 = blockIdx.x * TILE_N;

    // stage Sx rows (coalesced read, transposed LDS write)
    for (int idx = tid; idx < TILE_N * IN_F; idx += 256) {
        int n = idx >> 7, k = idx & 127;
        Sl[k * 36 + n] = Sx[(size_t)(n0 + n) * IN_F + k];
    }
    // stage Se rows
    for (int idx = tid; idx < TILE_N * EDGE_F; idx += 256) {
        int n = idx >> 4, k = idx & 15;
        Sl[(IN_F + k) * 36 + n] = Se[(size_t)(n0 + n) * EDGE_F + k];
    }

    float4 a0 = make_float4(0,0,0,0), a1 = make_float4(0,0,0,0);
    float4 a2 = make_float4(0,0,0,0), a3 = make_float4(0,0,0,0);

    for (int half = 0; half < 2; ++half) {
        __syncthreads();   // S staged (half 0) / prev half compute done
        int kbase = half * 72;
        for (int idx = tid; idx < 72 * 128; idx += 256) {
            int o = idx / 72, kl = idx % 72;          // coalesced W read
            Wt[kl * 132 + o] = W[(size_t)o * K_TOT + kbase + kl];
        }
        __syncthreads();

        #pragma unroll 4
        for (int kl = 0; kl < 72; ++kl) {
            float4 w4 = *(const float4*)&Wt[kl * 132 + to4];
            float4 s4 = *(const float4*)&Sl[(kbase + kl) * 36 + tn4];
            a0.x += s4.x * w4.x; a0.y += s4.x * w4.y; a0.z += s4.x * w4.z; a0.w += s4.x * w4.w;
            a1.x += s4.y * w4.x; a1.y += s4.y * w4.y; a1.z += s4.y * w4.z; a1.w += s4.y * w4.w;
            a2.x += s4.z * w4.x; a2.y += s4.z * w4.y; a2.z += s4.z * w4.z; a2.w += s4.z * w4.w;
            a3.x += s4.w * w4.x; a3.y += s4.w * w4.y; a3.z += s4.w * w4.z; a3.w += s4.w * w4.w;
        }
    }

    float4 b4 = *(const float4*)&b[to4];
    float4 accs[4] = {a0, a1, a2, a3};
    #pragma unroll
    for (int j = 0; j < 4; ++j) {
        int n = n0 + tn4 + j;
        float fdeg = (float)(offsets[n + 1] - offsets[n]);
        float inv = 1.0f / fmaxf(fdeg, 1.0f);
        float4 o4;
        o4.x = (accs[j].x + fdeg * b4.x) * inv;
        o4.y = (accs[j].y + fdeg * b4.y) * inv;
        o4.z = (accs[j].z + fdeg * b4.z) * inv;
        o4.w = (accs[j].w + fdeg * b4.w) * inv;
        *(float4*)&out[(size_t)n * OUT_F + to4] = o4;
    }
}

extern "C" void kernel_launch(void* const* d_in, const int* in_sizes, int n_in,
                              void* d_out, int out_size, void* d_ws, size_t ws_size,
                              hipStream_t stream) {
    const float* x  = (const float*)d_in[0];
    const int*   ei = (const int*)d_in[1];     // int32 per harness convention
    const float* ea = (const float*)d_in[2];
    const float* W  = (const float*)d_in[3];
    const float* b  = (const float*)d_in[4];
    float* out = (float*)d_out;

    char* ws = (char*)d_ws;
    int*   counts   = (int*)(ws + 0);
    int*   offsets  = (int*)(ws + 400000);
    int*   partials = (int*)(ws + 800016);
    int*   cursors  = (int*)(ws + 801040);
    int*   csr      = (int*)(ws + 1201040);
    float* Se       = (float*)(ws + 14001040);

    const int* row = ei;             // edge_index[0]
    const int* col = ei + N_EDGES;   // edge_index[1]

    hipMemsetAsync(counts, 0, N_NODES * sizeof(int), stream);
    count_k<<<(N_EDGES + 255) / 256, 256, 0, stream>>>(col, counts);
    scan1_k<<<196, 512, 0, stream>>>(counts, offsets, partials);
    scan2_k<<<1, 256, 0, stream>>>(partials);
    scan3_k<<<196, 512, 0, stream>>>(offsets, partials, cursors);
    fill_k<<<(N_EDGES + 255) / 256, 256, 0, stream>>>(col, cursors, csr);
    gather_k<<<N_NODES / 4, 256, 0, stream>>>(x, row, ea, offsets, csr, out, Se);
    gemm_k<<<3125, 256, 0, stream>>>(out, Se, offsets, W, b, out);
}